// Round 5
// baseline (726.449 us; speedup 1.0000x reference)
//
#include <hip/hip_runtime.h>

#define Bsz 512
#define Tsz 64
#define Hsz 512

typedef __attribute__((ext_vector_type(8))) short bf16x8;
typedef __attribute__((ext_vector_type(4))) float f32x4;

__device__ __forceinline__ unsigned short f2bf(float f) {
  union { float f; unsigned int u; } a; a.f = f;
  unsigned int u = a.u;
  unsigned int lsb = (u >> 16) & 1;
  u += 0x7fffu + lsb;   // round-to-nearest-even
  return (unsigned short)(u >> 16);
}

__device__ __forceinline__ void gload16(const void* g, void* l) {
  __builtin_amdgcn_global_load_lds(
      (const __attribute__((address_space(1))) unsigned int*)g,
      (__attribute__((address_space(3))) unsigned int*)l, 16, 0, 0);
}

__device__ __forceinline__ float sigm(float x) { return 1.f / (1.f + __expf(-x)); }
__device__ __forceinline__ float tanh_f(float x) { return 2.f / (1.f + __expf(-2.f * x)) - 1.f; }

// ---------------- converts ----------------
__global__ __launch_bounds__(256) void k_conv_x(const float* __restrict__ x,
                                                unsigned short* __restrict__ xbf) {
  int v = blockIdx.x * 256 + threadIdx.x;
  int e = v * 8;
  int i = e & 511;
  int t = (e >> 9) & 63;
  int b = e >> 15;
  float4 f0 = *(const float4*)(x + e);
  float4 f1 = *(const float4*)(x + e + 4);
  bf16x8 o;
  o[0] = (short)f2bf(f0.x); o[1] = (short)f2bf(f0.y);
  o[2] = (short)f2bf(f0.z); o[3] = (short)f2bf(f0.w);
  o[4] = (short)f2bf(f1.x); o[5] = (short)f2bf(f1.y);
  o[6] = (short)f2bf(f1.z); o[7] = (short)f2bf(f1.w);
  *(bf16x8*)(xbf + ((size_t)(t * 512 + b) << 9) + i) = o;
}

__global__ __launch_bounds__(256) void k_conv_w(
    const float* __restrict__ wihf, const float* __restrict__ whhf,
    const float* __restrict__ wihb, const float* __restrict__ whhb,
    const float* __restrict__ wlin,
    unsigned short* __restrict__ Wcat, unsigned short* __restrict__ wlinbf) {
  int v = blockIdx.x * 256 + threadIdx.x;
  const int nW = 2 * 16 * 128 * 128;
  if (v < nW) {
    int k8 = v & 127; int row = v >> 7;
    int c = row & 127, sl = (row >> 7) & 15, d = row >> 11;
    int g = c >> 5, hl = c & 31;
    int wr = g * 512 + sl * 32 + hl;
    int k = k8 * 8;
    const float* src;
    if (k < 512) src = (d ? wihb : wihf) + (size_t)wr * 512 + k;
    else         src = (d ? whhb : whhf) + (size_t)wr * 512 + (k - 512);
    float4 f0 = *(const float4*)src;
    float4 f1 = *(const float4*)(src + 4);
    bf16x8 o;
    o[0] = (short)f2bf(f0.x); o[1] = (short)f2bf(f0.y);
    o[2] = (short)f2bf(f0.z); o[3] = (short)f2bf(f0.w);
    o[4] = (short)f2bf(f1.x); o[5] = (short)f2bf(f1.y);
    o[6] = (short)f2bf(f1.z); o[7] = (short)f2bf(f1.w);
    *(bf16x8*)(Wcat + (size_t)row * 1024 + k) = o;
  } else {
    int v2 = v - nW;
    const float* src = wlin + (size_t)v2 * 8;
    float4 f0 = *(const float4*)src;
    float4 f1 = *(const float4*)(src + 4);
    bf16x8 o;
    o[0] = (short)f2bf(f0.x); o[1] = (short)f2bf(f0.y);
    o[2] = (short)f2bf(f0.z); o[3] = (short)f2bf(f0.w);
    o[4] = (short)f2bf(f1.x); o[5] = (short)f2bf(f1.y);
    o[6] = (short)f2bf(f1.z); o[7] = (short)f2bf(f1.w);
    *(bf16x8*)(wlinbf + (size_t)v2 * 8) = o;
  }
}

// ---------------- LSTM step: BK=128, 3-buffer, 1 barrier/chunk, counted vmcnt ----------------
// grid 256: blockIdx = mt*32 + (sl*2 + dir) ; tile [64 batch][128 cols], K=1024 (8 chunks of 128)
// LDS buf = A[64][128]bf16 (16KB, 1024 chunks) + B[128][128]bf16 (32KB, 2048 chunks) = 48KB
// 3 bufs = 144KB; epilogue sD f32[64][128] reuses buf0
__global__ __launch_bounds__(256) void k_step(
    const unsigned short* __restrict__ xf, const unsigned short* __restrict__ xb,
    const unsigned short* __restrict__ hpf, const unsigned short* __restrict__ hpb,
    const unsigned short* __restrict__ Wcat,
    const float* __restrict__ biasf, const float* __restrict__ biasb,
    float* __restrict__ c_all,
    unsigned short* __restrict__ hof, unsigned short* __restrict__ hob) {
  extern __shared__ char smem[];
  const int tid = threadIdx.x;
  const int g32 = blockIdx.x & 31;
  const int mt  = blockIdx.x >> 5;
  const int dir = g32 & 1;
  const int sl  = g32 >> 1;
  const int b0  = mt * 64;

  const unsigned short* xd = dir ? xb : xf;
  const unsigned short* hd = dir ? hpb : hpf;
  const unsigned short* Wd = Wcat + (size_t)(dir * 16 + sl) * (128 * 1024);
  const float* bias = dir ? biasb : biasf;
  float* cd = c_all + (size_t)dir * (Bsz * Hsz);
  unsigned short* hod = dir ? hob : hof;

  const int lane = tid & 63;
  const int wv = tid >> 6;
  const int wr = wv >> 1, wc = wv & 1;
  const int l15 = lane & 15, l4 = lane >> 4;

  const f32x4 z4 = {0.f, 0.f, 0.f, 0.f};
  f32x4 acc[2][4];
#pragma unroll
  for (int i = 0; i < 2; ++i)
#pragma unroll
    for (int j = 0; j < 4; ++j) acc[i][j] = z4;

  // stage chunk kc (128 K-cols) into buf: A = 4*256 chunks, B = 8*256 chunks (12 loads/thread)
  auto STAGE = [&](int kc, char* buf) {
    const unsigned short* Asrc = (kc < 4) ? xd : hd;
    const int koff = (kc & 3) * 128;
#pragma unroll
    for (int it = 0; it < 4; ++it) {
      int idx = it * 256 + tid;
      int row = idx >> 4, g = idx & 15;   // row 0..63, 16 groups of 16B per row
      int sc = g ^ (row & 7);
      gload16(Asrc + (size_t)(b0 + row) * 512 + koff + sc * 8, buf + idx * 16);
    }
#pragma unroll
    for (int it = 0; it < 8; ++it) {
      int idx = it * 256 + tid;
      int row = idx >> 4, g = idx & 15;   // row 0..127
      int sc = g ^ (row & 7);
      gload16(Wd + (size_t)row * 1024 + kc * 128 + sc * 8, buf + 16384 + idx * 16);
    }
  };

  // prologue: stage chunk 0 into buf0
  STAGE(0, smem);

  for (int m = 0; m < 8; ++m) {
    char* cur = smem + (m % 3) * 49152;
    if (m < 7) {
      STAGE(m + 1, smem + ((m + 1) % 3) * 49152);
      asm volatile("s_waitcnt vmcnt(12)" ::: "memory");  // chunk m's 12 loads landed; m+1's 12 in flight
    } else {
      asm volatile("s_waitcnt vmcnt(0)" ::: "memory");
    }
    __builtin_amdgcn_s_barrier();

#pragma unroll
    for (int ks = 0; ks < 4; ++ks) {
      bf16x8 a[2], b[4];
      int sb = ks * 4 + l4;
#pragma unroll
      for (int mi = 0; mi < 2; ++mi) {
        int row = wr * 32 + mi * 16 + l15;
        a[mi] = *(const bf16x8*)(cur + row * 256 + (sb ^ (row & 7)) * 16);
      }
#pragma unroll
      for (int ni = 0; ni < 4; ++ni) {
        int row = wc * 64 + ni * 16 + l15;
        b[ni] = *(const bf16x8*)(cur + 16384 + row * 256 + (sb ^ (row & 7)) * 16);
      }
#pragma unroll
      for (int mi = 0; mi < 2; ++mi)
#pragma unroll
        for (int ni = 0; ni < 4; ++ni)
          acc[mi][ni] = __builtin_amdgcn_mfma_f32_16x16x32_bf16(a[mi], b[ni], acc[mi][ni], 0, 0, 0);
    }
    // no trailing barrier: buf being restaged at iter m+1 was last READ at iter m-1,
    // and those ds_reads are consumed (lgkm-waited) before each wave reaches iter m's barrier.
  }
  __syncthreads();

  // dump acc -> sD [64][128] f32, bank-swizzled: col ^= ((row>>2)&3)<<4
  float* sD = (float*)smem;
#pragma unroll
  for (int mi = 0; mi < 2; ++mi)
#pragma unroll
    for (int ni = 0; ni < 4; ++ni) {
      int rowb = wr * 32 + mi * 16 + l4 * 4;
      int col = wc * 64 + ni * 16 + l15;
#pragma unroll
      for (int r = 0; r < 4; ++r) {
        int rr = rowb + r;
        sD[rr * 128 + (col ^ (((rr >> 2) & 3) << 4))] = acc[mi][ni][r];
      }
    }
  __syncthreads();

  const int hl = tid & 31;
  const int r0 = tid >> 5;
  const int hcg = sl * 32 + hl;
  const float bi = bias[hcg], bff = bias[512 + hcg], bg = bias[1024 + hcg], bo = bias[1536 + hcg];
#pragma unroll
  for (int ii = 0; ii < 8; ++ii) {
    int row = r0 + ii * 8;
    int sw = ((row >> 2) & 3) << 4;
    float iv = sD[row * 128 + ((0  + hl) ^ sw)] + bi;
    float fv = sD[row * 128 + ((32 + hl) ^ sw)] + bff;
    float gv = sD[row * 128 + ((64 + hl) ^ sw)] + bg;
    float ov = sD[row * 128 + ((96 + hl) ^ sw)] + bo;
    float ig = sigm(iv);
    float fg = sigm(fv);
    float gg = tanh_f(gv);
    float og = sigm(ov);
    size_t gi = (size_t)(b0 + row) * Hsz + hcg;
    float cn = fg * cd[gi] + ig * gg;
    cd[gi] = cn;
    float hn = og * tanh_f(cn);
    hod[gi] = f2bf(hn);
  }
}

// ---------------- output GEMM (unchanged: 4 WG/CU, HBM-bound) ----------------
__global__ __launch_bounds__(256) void k_out(
    const unsigned short* __restrict__ hsf, const unsigned short* __restrict__ hsb,
    const unsigned short* __restrict__ wlin, const float* __restrict__ blin,
    float* __restrict__ out) {
  extern __shared__ char smem[];
  const int tid = threadIdx.x;
  const int mt = blockIdx.x >> 2;
  const int nt = blockIdx.x & 3;
  const int m0 = mt * 128, n0 = nt * 128;
  const int lane = tid & 63, wv = tid >> 6;
  const int wr = wv >> 1, wc = wv & 1;
  const int l15 = lane & 15, l4 = lane >> 4;

  const f32x4 z4 = {0.f, 0.f, 0.f, 0.f};
  f32x4 acc[4][4];
#pragma unroll
  for (int i = 0; i < 4; ++i)
#pragma unroll
    for (int j = 0; j < 4; ++j) acc[i][j] = z4;

  for (int kc = 0; kc < 16; ++kc) {
    if (kc) __syncthreads();
    const unsigned short* Asrc = (kc < 8) ? hsf : hsb;
    const int kk = (kc & 7) * 64;
#pragma unroll
    for (int it = 0; it < 4; ++it) {
      int idx = it * 256 + tid;
      int row = idx >> 3, c16 = idx & 7;
      int sc = c16 ^ (row & 7);
      gload16(Asrc + (size_t)(m0 + row) * 512 + kk + sc * 8, smem + idx * 16);
    }
#pragma unroll
    for (int it = 0; it < 4; ++it) {
      int idx = it * 256 + tid;
      int row = idx >> 3, c16 = idx & 7;
      int sc = c16 ^ (row & 7);
      gload16(wlin + (size_t)(n0 + row) * 1024 + kc * 64 + sc * 8, smem + 16384 + idx * 16);
    }
    __syncthreads();
#pragma unroll
    for (int ks = 0; ks < 2; ++ks) {
      bf16x8 a[4], b[4];
      int sb = ks * 4 + l4;
#pragma unroll
      for (int mi = 0; mi < 4; ++mi) {
        int row = wr * 64 + mi * 16 + l15;
        a[mi] = *(const bf16x8*)(smem + row * 128 + (sb ^ (row & 7)) * 16);
      }
#pragma unroll
      for (int ni = 0; ni < 4; ++ni) {
        int row = wc * 64 + ni * 16 + l15;
        b[ni] = *(const bf16x8*)(smem + 16384 + row * 128 + (sb ^ (row & 7)) * 16);
      }
#pragma unroll
      for (int mi = 0; mi < 4; ++mi)
#pragma unroll
        for (int ni = 0; ni < 4; ++ni)
          acc[mi][ni] = __builtin_amdgcn_mfma_f32_16x16x32_bf16(a[mi], b[ni], acc[mi][ni], 0, 0, 0);
    }
  }
#pragma unroll
  for (int mi = 0; mi < 4; ++mi)
#pragma unroll
    for (int ni = 0; ni < 4; ++ni) {
      int cc = n0 + wc * 64 + ni * 16 + l15;
      float bl = blin[cc];
#pragma unroll
      for (int r = 0; r < 4; ++r) {
        int rr = m0 + wr * 64 + mi * 16 + l4 * 4 + r;
        int b = rr & 511, t = rr >> 9;
        out[(size_t)(b * 64 + t) * 512 + cc] = acc[mi][ni][r] + bl;
      }
    }
}

extern "C" void kernel_launch(void* const* d_in, const int* in_sizes, int n_in,
                              void* d_out, int out_size, void* d_ws, size_t ws_size,
                              hipStream_t stream) {
  const float* x     = (const float*)d_in[0];
  const float* wih_f = (const float*)d_in[1];
  const float* whh_f = (const float*)d_in[2];
  const float* b_f   = (const float*)d_in[3];
  const float* wih_b = (const float*)d_in[4];
  const float* whh_b = (const float*)d_in[5];
  const float* b_b   = (const float*)d_in[6];
  const float* wlin  = (const float*)d_in[7];
  const float* blin  = (const float*)d_in[8];
  float* out = (float*)d_out;

  char* ws = (char*)d_ws;
  unsigned short* Wcat   = (unsigned short*)(ws + 0);
  unsigned short* wlinbf = (unsigned short*)(ws + 8388608);
  unsigned short* xbf    = (unsigned short*)(ws + 9437184);
  unsigned short* hsf    = (unsigned short*)(ws + 42991616);
  unsigned short* hsb    = (unsigned short*)(ws + 76546048);
  float*          c_all  = (float*)(ws + 110100480);
  unsigned short* h0     = (unsigned short*)(ws + 112197632);

  hipMemsetAsync(c_all, 0, 2097152, stream);
  hipMemsetAsync(h0, 0, 524288, stream);
  k_conv_x<<<8192, 256, 0, stream>>>(x, xbf);
  k_conv_w<<<2304, 256, 0, stream>>>(wih_f, whh_f, wih_b, whh_b, wlin, Wcat, wlinbf);

  const size_t BH = (size_t)Bsz * Hsz;
  for (int s = 0; s < 64; ++s) {
    int tf = s, tb = 63 - s;
    const unsigned short* xfp = xbf + (size_t)tf * BH;
    const unsigned short* xbp = xbf + (size_t)tb * BH;
    const unsigned short* hpf = s ? hsf + (size_t)(tf - 1) * BH : h0;
    const unsigned short* hpb = s ? hsb + (size_t)(tb + 1) * BH : h0;
    k_step<<<256, 256, 147456, stream>>>(xfp, xbp, hpf, hpb, Wcat, b_f, b_b,
                                         c_all, hsf + (size_t)tf * BH, hsb + (size_t)tb * BH);
  }
  k_out<<<1024, 256, 32768, stream>>>(hsf, hsb, wlinbf, blin, out);
}

// Round 6
// 666.185 us; speedup vs baseline: 1.0905x; 1.0905x over previous
//
#include <hip/hip_runtime.h>

#define Bsz 512
#define Tsz 64
#define Hsz 512

typedef __attribute__((ext_vector_type(8))) short bf16x8;
typedef __attribute__((ext_vector_type(4))) float f32x4;

__device__ __forceinline__ unsigned short f2bf(float f) {
  union { float f; unsigned int u; } a; a.f = f;
  unsigned int u = a.u;
  unsigned int lsb = (u >> 16) & 1;
  u += 0x7fffu + lsb;   // round-to-nearest-even
  return (unsigned short)(u >> 16);
}

__device__ __forceinline__ void gload16(const void* g, void* l) {
  __builtin_amdgcn_global_load_lds(
      (const __attribute__((address_space(1))) unsigned int*)g,
      (__attribute__((address_space(3))) unsigned int*)l, 16, 0, 0);
}

__device__ __forceinline__ float sigm(float x) { return 1.f / (1.f + __expf(-x)); }
__device__ __forceinline__ float tanh_f(float x) { return 2.f / (1.f + __expf(-2.f * x)) - 1.f; }

// ---------------- converts ----------------
__global__ __launch_bounds__(256) void k_conv_x(const float* __restrict__ x,
                                                unsigned short* __restrict__ xbf) {
  int v = blockIdx.x * 256 + threadIdx.x;
  int e = v * 8;
  int i = e & 511;
  int t = (e >> 9) & 63;
  int b = e >> 15;
  float4 f0 = *(const float4*)(x + e);
  float4 f1 = *(const float4*)(x + e + 4);
  bf16x8 o;
  o[0] = (short)f2bf(f0.x); o[1] = (short)f2bf(f0.y);
  o[2] = (short)f2bf(f0.z); o[3] = (short)f2bf(f0.w);
  o[4] = (short)f2bf(f1.x); o[5] = (short)f2bf(f1.y);
  o[6] = (short)f2bf(f1.z); o[7] = (short)f2bf(f1.w);
  *(bf16x8*)(xbf + ((size_t)(t * 512 + b) << 9) + i) = o;
}

__global__ __launch_bounds__(256) void k_conv_w(
    const float* __restrict__ wihf, const float* __restrict__ whhf,
    const float* __restrict__ wihb, const float* __restrict__ whhb,
    const float* __restrict__ wlin,
    unsigned short* __restrict__ Wcat, unsigned short* __restrict__ wlinbf) {
  int v = blockIdx.x * 256 + threadIdx.x;
  const int nW = 2 * 16 * 128 * 128;
  if (v < nW) {
    int k8 = v & 127; int row = v >> 7;
    int c = row & 127, sl = (row >> 7) & 15, d = row >> 11;
    int g = c >> 5, hl = c & 31;
    int wr = g * 512 + sl * 32 + hl;
    int k = k8 * 8;
    const float* src;
    if (k < 512) src = (d ? wihb : wihf) + (size_t)wr * 512 + k;
    else         src = (d ? whhb : whhf) + (size_t)wr * 512 + (k - 512);
    float4 f0 = *(const float4*)src;
    float4 f1 = *(const float4*)(src + 4);
    bf16x8 o;
    o[0] = (short)f2bf(f0.x); o[1] = (short)f2bf(f0.y);
    o[2] = (short)f2bf(f0.z); o[3] = (short)f2bf(f0.w);
    o[4] = (short)f2bf(f1.x); o[5] = (short)f2bf(f1.y);
    o[6] = (short)f2bf(f1.z); o[7] = (short)f2bf(f1.w);
    *(bf16x8*)(Wcat + (size_t)row * 1024 + k) = o;
  } else {
    int v2 = v - nW;
    const float* src = wlin + (size_t)v2 * 8;
    float4 f0 = *(const float4*)src;
    float4 f1 = *(const float4*)(src + 4);
    bf16x8 o;
    o[0] = (short)f2bf(f0.x); o[1] = (short)f2bf(f0.y);
    o[2] = (short)f2bf(f0.z); o[3] = (short)f2bf(f0.w);
    o[4] = (short)f2bf(f1.x); o[5] = (short)f2bf(f1.y);
    o[6] = (short)f2bf(f1.z); o[7] = (short)f2bf(f1.w);
    *(bf16x8*)(wlinbf + (size_t)v2 * 8) = o;
  }
}

// ---------------- LSTM step: BK=64, 5-buffer, prefetch depth 3, counted vmcnt ----------------
// grid 256: blockIdx = mt*32 + (sl*2 + dir); tile [64 batch][128 cols], K=1024 (16 chunks of 64)
// buf = A[64][64]bf16 (8KB) + B[128][64]bf16 (16KB) = 24KB; 5 bufs = 120KB; sD f32[64][128] reuses base
// Safety: STAGE at iter m overwrites buf[(m+3)%5] == buf read at iter m-2; all waves passed
// barrier(m-1) before any iter-m STAGE, and iter-(m-2) ds_reads retire before barrier(m-1). d<=N-2 OK.
__global__ __launch_bounds__(256) void k_step(
    const unsigned short* __restrict__ xf, const unsigned short* __restrict__ xb,
    const unsigned short* __restrict__ hpf, const unsigned short* __restrict__ hpb,
    const unsigned short* __restrict__ Wcat,
    const float* __restrict__ biasf, const float* __restrict__ biasb,
    float* __restrict__ c_all,
    unsigned short* __restrict__ hof, unsigned short* __restrict__ hob) {
  extern __shared__ char smem[];
  const int tid = threadIdx.x;
  const int g32 = blockIdx.x & 31;
  const int mt  = blockIdx.x >> 5;
  const int dir = g32 & 1;
  const int sl  = g32 >> 1;
  const int b0  = mt * 64;

  const unsigned short* xd = dir ? xb : xf;
  const unsigned short* hd = dir ? hpb : hpf;
  const unsigned short* Wd = Wcat + (size_t)(dir * 16 + sl) * (128 * 1024);
  const float* bias = dir ? biasb : biasf;
  float* cd = c_all + (size_t)dir * (Bsz * Hsz);
  unsigned short* hod = dir ? hob : hof;

  const int lane = tid & 63;
  const int wv = tid >> 6;
  const int wr = wv >> 1, wc = wv & 1;
  const int l15 = lane & 15, l4 = lane >> 4;

  // ---- early loads (oldest in vmcnt order): c state + biases, consumed in the tail ----
  const int hl = tid & 31;
  const int r0 = tid >> 5;
  const int hcg = sl * 32 + hl;
  float cv[8];
#pragma unroll
  for (int ii = 0; ii < 8; ++ii)
    cv[ii] = cd[(size_t)(b0 + r0 + ii * 8) * Hsz + hcg];
  const float bi = bias[hcg], bff = bias[512 + hcg], bg = bias[1024 + hcg], bo = bias[1536 + hcg];

  const f32x4 z4 = {0.f, 0.f, 0.f, 0.f};
  f32x4 acc[2][4];
#pragma unroll
  for (int i = 0; i < 2; ++i)
#pragma unroll
    for (int j = 0; j < 4; ++j) acc[i][j] = z4;

  // stage chunk kc (64 K-cols): A 2 insts/thread, B 4 insts/thread = 6 loads
  auto STAGE = [&](int kc, char* buf) {
    const unsigned short* Asrc = (kc < 8) ? xd : hd;
    const int koff = (kc & 7) * 64;
#pragma unroll
    for (int it = 0; it < 2; ++it) {
      int idx = it * 256 + tid;
      int row = idx >> 3, g = idx & 7;
      int sc = g ^ (row & 7);
      gload16(Asrc + (size_t)(b0 + row) * 512 + koff + sc * 8, buf + idx * 16);
    }
#pragma unroll
    for (int it = 0; it < 4; ++it) {
      int idx = it * 256 + tid;
      int row = idx >> 3, g = idx & 7;
      int sc = g ^ (row & 7);
      gload16(Wd + (size_t)row * 1024 + kc * 64 + sc * 8, buf + 8192 + idx * 16);
    }
  };

  // prologue: stage chunks 0,1,2
  STAGE(0, smem);
  STAGE(1, smem + 24576);
  STAGE(2, smem + 49152);

  for (int m = 0; m < 16; ++m) {
    char* cur = smem + (m % 5) * 24576;
    if (m < 13) {
      STAGE(m + 3, smem + ((m + 3) % 5) * 24576);
      asm volatile("s_waitcnt vmcnt(18)" ::: "memory");  // chunk m landed; m+1..m+3 (18) in flight
    } else if (m == 13) {
      asm volatile("s_waitcnt vmcnt(12)" ::: "memory");
    } else if (m == 14) {
      asm volatile("s_waitcnt vmcnt(6)" ::: "memory");
    } else {
      asm volatile("s_waitcnt vmcnt(0)" ::: "memory");
    }
    __builtin_amdgcn_s_barrier();

#pragma unroll
    for (int ks = 0; ks < 2; ++ks) {
      bf16x8 a[2], b[4];
      int sb = ks * 4 + l4;
#pragma unroll
      for (int mi = 0; mi < 2; ++mi) {
        int row = wr * 32 + mi * 16 + l15;
        a[mi] = *(const bf16x8*)(cur + row * 128 + (sb ^ (row & 7)) * 16);
      }
#pragma unroll
      for (int ni = 0; ni < 4; ++ni) {
        int row = wc * 64 + ni * 16 + l15;
        b[ni] = *(const bf16x8*)(cur + 8192 + row * 128 + (sb ^ (row & 7)) * 16);
      }
#pragma unroll
      for (int mi = 0; mi < 2; ++mi)
#pragma unroll
        for (int ni = 0; ni < 4; ++ni)
          acc[mi][ni] = __builtin_amdgcn_mfma_f32_16x16x32_bf16(a[mi], b[ni], acc[mi][ni], 0, 0, 0);
    }
  }
  __syncthreads();

  // dump acc -> sD [64][128] f32, bank-swizzled: col ^= ((row>>2)&3)<<4
  float* sD = (float*)smem;
#pragma unroll
  for (int mi = 0; mi < 2; ++mi)
#pragma unroll
    for (int ni = 0; ni < 4; ++ni) {
      int rowb = wr * 32 + mi * 16 + l4 * 4;
      int col = wc * 64 + ni * 16 + l15;
#pragma unroll
      for (int r = 0; r < 4; ++r) {
        int rr = rowb + r;
        sD[rr * 128 + (col ^ (((rr >> 2) & 3) << 4))] = acc[mi][ni][r];
      }
    }
  __syncthreads();

#pragma unroll
  for (int ii = 0; ii < 8; ++ii) {
    int row = r0 + ii * 8;
    int sw = ((row >> 2) & 3) << 4;
    float iv = sD[row * 128 + ((0  + hl) ^ sw)] + bi;
    float fv = sD[row * 128 + ((32 + hl) ^ sw)] + bff;
    float gv = sD[row * 128 + ((64 + hl) ^ sw)] + bg;
    float ov = sD[row * 128 + ((96 + hl) ^ sw)] + bo;
    float ig = sigm(iv);
    float fg = sigm(fv);
    float gg = tanh_f(gv);
    float og = sigm(ov);
    size_t gi = (size_t)(b0 + row) * Hsz + hcg;
    float cn = fg * cv[ii] + ig * gg;
    cd[gi] = cn;
    float hn = og * tanh_f(cn);
    hod[gi] = f2bf(hn);
  }
}

// ---------------- output GEMM: XCD-swizzled so A-panel sharers are co-XCD ----------------
__global__ __launch_bounds__(256) void k_out(
    const unsigned short* __restrict__ hsf, const unsigned short* __restrict__ hsb,
    const unsigned short* __restrict__ wlin, const float* __restrict__ blin,
    float* __restrict__ out) {
  extern __shared__ char smem[];
  const int tid = threadIdx.x;
  const int bidx = blockIdx.x;
  // b&7 = XCD (round-robin); the 4 nt-blocks of one mt share b&7 -> same XCD L2 keeps the A panel
  const int mt = (bidx & 7) + 8 * (bidx >> 5);
  const int nt = (bidx >> 3) & 3;
  const int m0 = mt * 128, n0 = nt * 128;
  const int lane = tid & 63, wv = tid >> 6;
  const int wr = wv >> 1, wc = wv & 1;
  const int l15 = lane & 15, l4 = lane >> 4;

  const f32x4 z4 = {0.f, 0.f, 0.f, 0.f};
  f32x4 acc[4][4];
#pragma unroll
  for (int i = 0; i < 4; ++i)
#pragma unroll
    for (int j = 0; j < 4; ++j) acc[i][j] = z4;

  for (int kc = 0; kc < 16; ++kc) {
    if (kc) __syncthreads();
    const unsigned short* Asrc = (kc < 8) ? hsf : hsb;
    const int kk = (kc & 7) * 64;
#pragma unroll
    for (int it = 0; it < 4; ++it) {
      int idx = it * 256 + tid;
      int row = idx >> 3, c16 = idx & 7;
      int sc = c16 ^ (row & 7);
      gload16(Asrc + (size_t)(m0 + row) * 512 + kk + sc * 8, smem + idx * 16);
    }
#pragma unroll
    for (int it = 0; it < 4; ++it) {
      int idx = it * 256 + tid;
      int row = idx >> 3, c16 = idx & 7;
      int sc = c16 ^ (row & 7);
      gload16(wlin + (size_t)(n0 + row) * 1024 + kc * 64 + sc * 8, smem + 16384 + idx * 16);
    }
    __syncthreads();
#pragma unroll
    for (int ks = 0; ks < 2; ++ks) {
      bf16x8 a[4], b[4];
      int sb = ks * 4 + l4;
#pragma unroll
      for (int mi = 0; mi < 4; ++mi) {
        int row = wr * 64 + mi * 16 + l15;
        a[mi] = *(const bf16x8*)(smem + row * 128 + (sb ^ (row & 7)) * 16);
      }
#pragma unroll
      for (int ni = 0; ni < 4; ++ni) {
        int row = wc * 64 + ni * 16 + l15;
        b[ni] = *(const bf16x8*)(smem + 16384 + row * 128 + (sb ^ (row & 7)) * 16);
      }
#pragma unroll
      for (int mi = 0; mi < 4; ++mi)
#pragma unroll
        for (int ni = 0; ni < 4; ++ni)
          acc[mi][ni] = __builtin_amdgcn_mfma_f32_16x16x32_bf16(a[mi], b[ni], acc[mi][ni], 0, 0, 0);
    }
  }
#pragma unroll
  for (int mi = 0; mi < 4; ++mi)
#pragma unroll
    for (int ni = 0; ni < 4; ++ni) {
      int cc = n0 + wc * 64 + ni * 16 + l15;
      float bl = blin[cc];
#pragma unroll
      for (int r = 0; r < 4; ++r) {
        int rr = m0 + wr * 64 + mi * 16 + l4 * 4 + r;
        int b = rr & 511, t = rr >> 9;
        out[(size_t)(b * 64 + t) * 512 + cc] = acc[mi][ni][r] + bl;
      }
    }
}

extern "C" void kernel_launch(void* const* d_in, const int* in_sizes, int n_in,
                              void* d_out, int out_size, void* d_ws, size_t ws_size,
                              hipStream_t stream) {
  const float* x     = (const float*)d_in[0];
  const float* wih_f = (const float*)d_in[1];
  const float* whh_f = (const float*)d_in[2];
  const float* b_f   = (const float*)d_in[3];
  const float* wih_b = (const float*)d_in[4];
  const float* whh_b = (const float*)d_in[5];
  const float* b_b   = (const float*)d_in[6];
  const float* wlin  = (const float*)d_in[7];
  const float* blin  = (const float*)d_in[8];
  float* out = (float*)d_out;

  char* ws = (char*)d_ws;
  unsigned short* Wcat   = (unsigned short*)(ws + 0);
  unsigned short* wlinbf = (unsigned short*)(ws + 8388608);
  unsigned short* xbf    = (unsigned short*)(ws + 9437184);
  unsigned short* hsf    = (unsigned short*)(ws + 42991616);
  unsigned short* hsb    = (unsigned short*)(ws + 76546048);
  float*          c_all  = (float*)(ws + 110100480);
  unsigned short* h0     = (unsigned short*)(ws + 112197632);

  hipMemsetAsync(c_all, 0, 2097152, stream);
  hipMemsetAsync(h0, 0, 524288, stream);
  k_conv_x<<<8192, 256, 0, stream>>>(x, xbf);
  k_conv_w<<<2304, 256, 0, stream>>>(wih_f, whh_f, wih_b, whh_b, wlin, Wcat, wlinbf);

  const size_t BH = (size_t)Bsz * Hsz;
  for (int s = 0; s < 64; ++s) {
    int tf = s, tb = 63 - s;
    const unsigned short* xfp = xbf + (size_t)tf * BH;
    const unsigned short* xbp = xbf + (size_t)tb * BH;
    const unsigned short* hpf = s ? hsf + (size_t)(tf - 1) * BH : h0;
    const unsigned short* hpb = s ? hsb + (size_t)(tb + 1) * BH : h0;
    k_step<<<256, 256, 122880, stream>>>(xfp, xbp, hpf, hpb, Wcat, b_f, b_b,
                                         c_all, hsf + (size_t)tf * BH, hsb + (size_t)tb * BH);
  }
  k_out<<<1024, 256, 32768, stream>>>(hsf, hsb, wlinbf, blin, out);
}